// Round 5
// baseline (147.721 us; speedup 1.0000x reference)
//
#include <hip/hip_runtime.h>

// y:   (B=32, K=64, n1=4, n2=8, n3=8) fp32
// W1d: (K,1,256,1,1) -> w1[k][i]
// W2d: (K,1,1,4,4)   -> w2[k][j][l]
// out[b, x*256+i, yy*4+j, z*4+l] = sum_k y[b,k,x,yy,z] * w1[k,i] * w2[k,j,l]
//
// Flat: out[(b*1024 + x*256 + i)*1024 + c], c = yy*128 + j*32 + z*4 + l in [0,1024).
// s[k][c] = y[k,yy,z] * w2[k,j,l];  out[i][c] = sum_k w1[k,i] * s[k][c].
//
// Round-10 change: CONTIGUOUS-REGION BLOCKS (DRAM write locality).
// Rounds 6-9 proved instruction-level edits neutral: kernel stuck at ~60us =
// ~2.2 TB/s effective write BW vs 6.6 TB/s fill. Cause: old decomposition gave
// each block a 512B-per-4KB comb over 1 MB (c restricted to one yy) -> HBM
// sees ~512 interleaved streams of 512 B runs -> DRAM row thrash at ~1/3
// efficiency. New decomposition: block = (b, x, i-half) owns a CONTIGUOUS
// 512 KB of out. Block builds s for ALL 8 yy (sTall[1024][72] bf16, 144 KiB
// LDS), then each of 8 waves sweeps its 16-row i-tile across the full 4 KB row
// (ct = 0..63) -> rows complete quickly, 64 KB contiguous per wave, dense
// victim stream -> near-fill DRAM efficiency.
//
// mfma_f32_16x16x32_bf16 layouts (m89/m91-verified), operand order as validated:
//   acc = mfma(s_frag, w1_frag, acc):
//   A(s): lane holds s[c = ct*16+la][k = quad*8 + j]
//   B(w1): lane holds w1[k = quad*8 + j][i = i0 + la]
//   D: lane holds c = ct*16 + quad*4 + reg at i = i0 + la  -> f32x4 store at
//      out[row(i)*1024 + ct*16 + quad*4], contiguous across ct.
// sTall k-stride 72 ushorts (144 B, 16B-aligned): b128 reads 2-way bank alias
// (free, m136) — identical pattern to the validated LDK=72 layout.

typedef __bf16 bf16x8 __attribute__((ext_vector_type(8)));
typedef float  f32x4  __attribute__((ext_vector_type(4)));

#define LDK  72  // padded k-stride in ushorts for sTall
#define W2LD 68  // padded k-stride in floats for w2T

__device__ __forceinline__ unsigned short f2bf(float f) {
    union { float f; unsigned u; } v; v.f = f;
    unsigned r = v.u + 0x7fffu + ((v.u >> 16) & 1u);   // round-to-nearest-even
    return (unsigned short)(r >> 16);
}
__device__ __forceinline__ unsigned pack2(float a, float b) {
    return (unsigned)f2bf(a) | ((unsigned)f2bf(b) << 16);
}

// ---- pre-kernel: w1T[i*64 + k] = bf16(w1[k*256 + i]); 32 KiB, runs once.
__global__ __launch_bounds__(256)
void prep_w1(const float* __restrict__ w1, unsigned short* __restrict__ w1T) {
    int t = blockIdx.x * 256 + threadIdx.x;   // [0, 16384)
    int i = t >> 6, k = t & 63;
    w1T[t] = f2bf(w1[k * 256 + i]);
}

template <bool PRE>
__global__ __launch_bounds__(512, 1)
void backproj_kernel(const float* __restrict__ y,
                     const float* __restrict__ w1,
                     const unsigned short* __restrict__ w1T,
                     const float* __restrict__ w2,
                     float* __restrict__ out)
{
    __shared__ __align__(16) unsigned short sTall[1024 * LDK]; // 144 KiB : [c][k] bf16
    __shared__ float w2T[16 * W2LD];                           // 4.25 KiB: [jl][k]

    const int bid = blockIdx.x;           // [0, 256)
    const int ih = bid & 1;               // i-half
    const int x  = (bid >> 1) & 3;
    const int b  = bid >> 3;

    const int tid  = threadIdx.x;
    const int wv   = tid >> 6, lane = tid & 63;
    const int la   = lane & 15, quad = lane >> 4;
    const int i0   = ih * 128 + wv * 16;  // wave's i-tile base

    // ---- stage w2T[jl][k] (w2 is 64x16 floats = 256 float4s)
    if (tid < 256) {
        int k = tid >> 2, g = tid & 3;
        float4 wvv = ((const float4*)(w2 + k * 16))[g];
        w2T[(g * 4 + 0) * W2LD + k] = wvv.x;
        w2T[(g * 4 + 1) * W2LD + k] = wvv.y;
        w2T[(g * 4 + 2) * W2LD + k] = wvv.z;
        w2T[(g * 4 + 3) * W2LD + k] = wvv.w;
    }

    // ---- w1 fragments (MFMA B-operand), one i-tile per wave, K=64 in 2 frags.
    bf16x8 a0, a1;
    if (PRE) {
        const unsigned short* p = w1T + (i0 + la) * 64 + quad * 8;
        a0 = *(const bf16x8*)p;
        a1 = *(const bf16x8*)(p + 32);
    } else {
        const float* wcol = w1 + i0 + la;
        union { unsigned u[4]; bf16x8 v; } u0, u1;
        #pragma unroll
        for (int j2 = 0; j2 < 4; ++j2) {
            float f0 = wcol[(quad * 8 + 2 * j2) * 256];
            float f1 = wcol[(quad * 8 + 2 * j2 + 1) * 256];
            float g0 = wcol[(32 + quad * 8 + 2 * j2) * 256];
            float g1 = wcol[(32 + quad * 8 + 2 * j2 + 1) * 256];
            u0.u[j2] = pack2(f0, f1);
            u1.u[j2] = pack2(g0, g1);
        }
        a0 = u0.v; a1 = u1.v;
    }

    __syncthreads();   // w2T ready

    // ---- phase B: build sTall[c][k] = bf16(y[k, yy, z] * w2[k, jl]).
    // Each thread builds columns c0 = tid and c1 = tid + 512 (same j,z,l -> same
    // w2 column, shared f32x4 w2T reads; yy differs by 4). y read directly from
    // global (block slice = 16 KB, L1/L2-hot; per (k): 8 lanes broadcast-share).
    {
        const int c0  = tid, c1 = tid + 512;
        const int yy0 = c0 >> 7, yy1 = yy0 + 4;
        const int j   = (c0 >> 5) & 3, z = (c0 >> 2) & 7, l = c0 & 3;
        const int jl  = j * 4 + l;
        const float* yg0 = y + b * 16384 + x * 64 + yy0 * 8 + z;  // [k] stride 256
        const float* yg1 = y + b * 16384 + x * 64 + yy1 * 8 + z;
        unsigned* d0 = (unsigned*)&sTall[c0 * LDK];
        unsigned* d1 = (unsigned*)&sTall[c1 * LDK];
        #pragma unroll
        for (int q = 0; q < 16; ++q) {
            f32x4 wq = *(const f32x4*)&w2T[jl * W2LD + q * 4];
            float p0 = yg0[(q * 4 + 0) * 256], p1 = yg0[(q * 4 + 1) * 256];
            float p2 = yg0[(q * 4 + 2) * 256], p3 = yg0[(q * 4 + 3) * 256];
            float r0 = yg1[(q * 4 + 0) * 256], r1 = yg1[(q * 4 + 1) * 256];
            float r2 = yg1[(q * 4 + 2) * 256], r3 = yg1[(q * 4 + 3) * 256];
            d0[2 * q]     = pack2(p0 * wq[0], p1 * wq[1]);
            d0[2 * q + 1] = pack2(p2 * wq[2], p3 * wq[3]);
            d1[2 * q]     = pack2(r0 * wq[0], r1 * wq[1]);
            d1[2 * q + 1] = pack2(r2 * wq[2], r3 * wq[3]);
        }
    }
    __syncthreads();   // sTall ready

    // ---- sweep: wave wv covers rows i = i0 + [0,16) across the full 4 KB row
    // (c = 0..1023 in 64 ct-tiles), storing f32x4 contiguous in c.
    float* rowp = out + (size_t)(b * 1024 + x * 256 + i0 + la) * 1024 + quad * 4;
    #pragma unroll 4
    for (int ct = 0; ct < 64; ++ct) {
        const bf16x8 b0 = *(const bf16x8*)&sTall[(ct * 16 + la) * LDK + quad * 8];
        const bf16x8 b1 = *(const bf16x8*)&sTall[(ct * 16 + la) * LDK + 32 + quad * 8];
        f32x4 acc = (f32x4){0.f, 0.f, 0.f, 0.f};
        acc = __builtin_amdgcn_mfma_f32_16x16x32_bf16(b0, a0, acc, 0, 0, 0);
        acc = __builtin_amdgcn_mfma_f32_16x16x32_bf16(b1, a1, acc, 0, 0, 0);
        *(f32x4*)(rowp + ct * 16) = acc;
    }
}

extern "C" void kernel_launch(void* const* d_in, const int* in_sizes, int n_in,
                              void* d_out, int out_size, void* d_ws, size_t ws_size,
                              hipStream_t stream) {
    const float* y  = (const float*)d_in[0];
    const float* w1 = (const float*)d_in[1];   // (64, 256)
    const float* w2 = (const float*)d_in[2];   // (64, 16)
    float* out = (float*)d_out;

    // grid = 32 b x 4 x x 2 i-half = 256 blocks of 512 threads (1 block/CU)
    if (ws_size >= 32768 && d_ws != nullptr) {
        unsigned short* w1T = (unsigned short*)d_ws;
        prep_w1<<<dim3(64), dim3(256), 0, stream>>>(w1, w1T);
        backproj_kernel<true><<<dim3(256), dim3(512), 0, stream>>>(y, w1, w1T, w2, out);
    } else {
        backproj_kernel<false><<<dim3(256), dim3(512), 0, stream>>>(y, w1, nullptr, w2, out);
    }
}